// Round 1
// baseline (5538.419 us; speedup 1.0000x reference)
//
#include <hip/hip_runtime.h>

#define HID 32

__device__ __forceinline__ float fast_tanh(float x) {
    x = fminf(15.f, fmaxf(-15.f, x));
    float e = __expf(2.f * x);
    return (e - 1.f) / (e + 1.f);
}

// Computes xb[b] = x @ bases[b] (b=0,1) and agg = x @ loopw + bias
template<int IN>
__global__ void precompute_kernel(const float* __restrict__ xin, int xstride,
                                  const float* __restrict__ bases,  // [2, IN, 32]
                                  const float* __restrict__ loopw,  // [IN, 32]
                                  const float* __restrict__ bias,   // [32]
                                  float* __restrict__ xb0,
                                  float* __restrict__ xb1,
                                  float* __restrict__ agg,
                                  int n_nodes) {
    int idx = blockIdx.x * blockDim.x + threadIdx.x;
    if (idx >= n_nodes * HID) return;
    int n = idx >> 5, c = idx & 31;
    const float* xr = xin + (size_t)n * xstride;
    float s0 = 0.f, s1 = 0.f, sl = 0.f;
#pragma unroll
    for (int i = 0; i < IN; i++) {
        float xv = xr[i];
        s0 = fmaf(xv, bases[i * HID + c], s0);
        s1 = fmaf(xv, bases[(IN + i) * HID + c], s1);
        sl = fmaf(xv, loopw[i * HID + c], sl);
    }
    xb0[idx] = s0;
    xb1[idx] = s1;
    agg[idx] = sl + bias[c];
}

// 8 threads per edge; each handles 4 channels (float4 gather, 4 atomic adds)
__global__ void edge_kernel(const int* __restrict__ src, const int* __restrict__ dst,
                            const int* __restrict__ etype, const float* __restrict__ comp, // [R,2]
                            const float* __restrict__ xb0, const float* __restrict__ xb1,
                            float* __restrict__ agg, int E) {
    int t = blockIdx.x * blockDim.x + threadIdx.x;
    int e = t >> 3;
    if (e >= E) return;
    int lane = t & 7;
    int s = src[e], d = dst[e], r = etype[e];
    float c0 = comp[r * 2 + 0], c1 = comp[r * 2 + 1];
    float4 a = ((const float4*)(xb0 + (size_t)s * HID))[lane];
    float4 b = ((const float4*)(xb1 + (size_t)s * HID))[lane];
    float* o = agg + (size_t)d * HID + lane * 4;
    atomicAdd(o + 0, fmaf(c0, a.x, c1 * b.x));
    atomicAdd(o + 1, fmaf(c0, a.y, c1 * b.y));
    atomicAdd(o + 2, fmaf(c0, a.z, c1 * b.z));
    atomicAdd(o + 3, fmaf(c0, a.w, c1 * b.w));
}

__global__ void tanh_kernel(const float* __restrict__ agg, float* __restrict__ C,
                            int col_off, int n_nodes) {
    int idx = blockIdx.x * blockDim.x + threadIdx.x;
    if (idx >= n_nodes * HID) return;
    int n = idx >> 5, c = idx & 31;
    C[(size_t)n * 128 + col_off + c] = fast_tanh(agg[idx]);
}

#define NG 16
// One block (128 threads) handles NG user/item pairs.
__global__ void mlp_kernel(const float* __restrict__ C, const int* __restrict__ uid,
                           const int* __restrict__ vid, const float* __restrict__ w1,
                           const float* __restrict__ bl1, const float* __restrict__ w2,
                           const float* __restrict__ bl2, float* __restrict__ out, int G) {
    __shared__ float f[NG][256];
    __shared__ float red[NG][128];
    int g0 = blockIdx.x * NG;
    int t = threadIdx.x;
    for (int i = t; i < NG * 256; i += 128) {
        int g = i >> 8, k = i & 255;
        int gg = g0 + g;
        float v = 0.f;
        if (gg < G) {
            int node = (k < 128) ? uid[gg] : vid[gg];
            v = C[(size_t)node * 128 + (k & 127)];
        }
        f[g][k] = v;
    }
    __syncthreads();
    float acc[NG];
    float b1v = bl1[t];
#pragma unroll
    for (int g = 0; g < NG; g++) acc[g] = b1v;
    for (int k = 0; k < 256; k++) {
        float wv = w1[k * 128 + t];
#pragma unroll
        for (int g = 0; g < NG; g++) acc[g] = fmaf(f[g][k], wv, acc[g]);
    }
    float w2v = w2[t];
#pragma unroll
    for (int g = 0; g < NG; g++) red[g][t] = fmaxf(acc[g], 0.f) * w2v;
    __syncthreads();
    int g = t >> 3, part = t & 7;
    float s = 0.f;
#pragma unroll
    for (int i = 0; i < 16; i++) s += red[g][part * 16 + i];
    s += __shfl_down(s, 4, 8);
    s += __shfl_down(s, 2, 8);
    s += __shfl_down(s, 1, 8);
    if (part == 0 && g0 + g < G) out[g0 + g] = s + bl2[0];
}

extern "C" void kernel_launch(void* const* d_in, const int* in_sizes, int n_in,
                              void* d_out, int out_size, void* d_ws, size_t ws_size,
                              hipStream_t stream) {
    const float* x   = (const float*)d_in[0];
    const int* src   = (const int*)d_in[1];
    const int* dst   = (const int*)d_in[2];
    const int* etype = (const int*)d_in[3];
    const int* uid   = (const int*)d_in[4];
    const int* vid   = (const int*)d_in[5];
    int N = in_sizes[0] / 4;
    int E = in_sizes[1];
    int G = in_sizes[4];

    float* ws  = (float*)d_ws;
    float* xb0 = ws;
    float* xb1 = xb0 + (size_t)N * HID;
    float* agg = xb1 + (size_t)N * HID;
    float* C   = agg + (size_t)N * HID;   // [N, 128]

    int nthreads = N * HID;
    int nblocks = (nthreads + 255) / 256;
    int eblocks = (E * 8 + 255) / 256;

    for (int l = 0; l < 4; l++) {
        const float* bases = (const float*)d_in[6 + l * 4];
        const float* comp  = (const float*)d_in[7 + l * 4];
        const float* loopw = (const float*)d_in[8 + l * 4];
        const float* bias  = (const float*)d_in[9 + l * 4];
        if (l == 0)
            precompute_kernel<4><<<nblocks, 256, 0, stream>>>(x, 4, bases, loopw, bias,
                                                              xb0, xb1, agg, N);
        else
            precompute_kernel<32><<<nblocks, 256, 0, stream>>>(C + (l - 1) * HID, 128, bases,
                                                               loopw, bias, xb0, xb1, agg, N);
        edge_kernel<<<eblocks, 256, 0, stream>>>(src, dst, etype, comp, xb0, xb1, agg, E);
        tanh_kernel<<<nblocks, 256, 0, stream>>>(agg, C, l * HID, N);
    }

    int gblocks = (G + NG - 1) / NG;
    mlp_kernel<<<gblocks, 128, 0, stream>>>(C, uid, vid,
                                            (const float*)d_in[22], (const float*)d_in[23],
                                            (const float*)d_in[24], (const float*)d_in[25],
                                            (float*)d_out, G);
}

// Round 2
// 1559.972 us; speedup vs baseline: 3.5503x; 3.5503x over previous
//
#include <hip/hip_runtime.h>
#include <hip/hip_fp16.h>

#define HID 32
#define R 5

__device__ __forceinline__ float fast_tanh(float x) {
    x = fminf(15.f, fmaxf(-15.f, x));
    float e = __expf(2.f * x);
    return (e - 1.f) / (e + 1.f);
}

// ---------------- CSR build (once per call; graph static across layers) ----------------

__global__ void zero_kernel(int* p, int n) {
    int i = blockIdx.x * blockDim.x + threadIdx.x;
    if (i < n) p[i] = 0;
}

__global__ void hist_kernel(const int* __restrict__ dst, int* __restrict__ deg, int E) {
    int e = blockIdx.x * blockDim.x + threadIdx.x;
    if (e < E) atomicAdd(&deg[dst[e]], 1);
}

// per-block exclusive scan; tmpex[i] = exclusive-within-block, bsum[b] = block total
__global__ void scan_partial(const int* __restrict__ deg, int* __restrict__ tmpex,
                             int* __restrict__ bsum, int n) {
    __shared__ int sh[256];
    int i = blockIdx.x * 256 + threadIdx.x;
    int v = (i < n) ? deg[i] : 0;
    sh[threadIdx.x] = v;
    __syncthreads();
    for (int off = 1; off < 256; off <<= 1) {
        int t = 0;
        if (threadIdx.x >= off) t = sh[threadIdx.x - off];
        __syncthreads();
        if (threadIdx.x >= off) sh[threadIdx.x] += t;
        __syncthreads();
    }
    if (i < n) tmpex[i] = sh[threadIdx.x] - v;
    if (threadIdx.x == 255) bsum[blockIdx.x] = sh[255];
}

// single-block exclusive scan of block sums (nb <= ~400)
__global__ void scan_bsum(int* bsum, int nb) {
    __shared__ int sh[256];
    __shared__ int carry_sh;
    if (threadIdx.x == 0) carry_sh = 0;
    __syncthreads();
    for (int base = 0; base < nb; base += 256) {
        int i = base + threadIdx.x;
        int v = (i < nb) ? bsum[i] : 0;
        sh[threadIdx.x] = v;
        __syncthreads();
        for (int off = 1; off < 256; off <<= 1) {
            int t = 0;
            if (threadIdx.x >= off) t = sh[threadIdx.x - off];
            __syncthreads();
            if (threadIdx.x >= off) sh[threadIdx.x] += t;
            __syncthreads();
        }
        int carry = carry_sh;
        if (i < nb) bsum[i] = sh[threadIdx.x] - v + carry;
        int tot = sh[255];
        __syncthreads();
        if (threadIdx.x == 0) carry_sh = carry + tot;
        __syncthreads();
    }
}

__global__ void scan_add(const int* __restrict__ tmpex, const int* __restrict__ bsum,
                         int* __restrict__ row_start, int* __restrict__ cursor, int n, int E) {
    int i = blockIdx.x * 256 + threadIdx.x;
    if (i < n) {
        int v = tmpex[i] + bsum[blockIdx.x];
        row_start[i] = v;
        cursor[i] = v;
    }
    if (i == 0) row_start[n] = E;
}

// sort edges by dst; pack (etype, src) into one int (src < 2^20, etype < 8)
__global__ void scatter_kernel(const int* __restrict__ src, const int* __restrict__ dst,
                               const int* __restrict__ etype, int* __restrict__ cursor,
                               int* __restrict__ es, int E) {
    int e = blockIdx.x * blockDim.x + threadIdx.x;
    if (e >= E) return;
    int pos = atomicAdd(&cursor[dst[e]], 1);
    es[pos] = src[e] | (etype[e] << 20);
}

// ---------------- per-layer kernels ----------------

// xr[r][n][c] = sum_i x[n,i] * (comp[r,0]*bases[0,i,c] + comp[r,1]*bases[1,i,c]), fp16
template<int IN>
__global__ void xr_kernel(const float* __restrict__ xin, int xstride,
                          const float* __restrict__ bases,  // [2, IN, 32]
                          const float* __restrict__ comp,   // [R, 2]
                          __half* __restrict__ xr, int N) {
    int idx = blockIdx.x * 256 + threadIdx.x;
    if (idx >= N * HID) return;
    int n = idx >> 5, c = idx & 31;
    int r = blockIdx.y;
    float c0 = comp[r * 2 + 0], c1 = comp[r * 2 + 1];
    const float* xrow = xin + (size_t)n * xstride;
    float s = 0.f;
#pragma unroll
    for (int i = 0; i < IN; i++) {
        float w = fmaf(c0, bases[i * HID + c], c1 * bases[(IN + i) * HID + c]);
        s = fmaf(xrow[i], w, s);
    }
    xr[((size_t)r * N + n) * HID + c] = __float2half(s);
}

// selfb = x @ loopw + bias
template<int IN>
__global__ void selfb_kernel(const float* __restrict__ xin, int xstride,
                             const float* __restrict__ loopw, const float* __restrict__ bias,
                             float* __restrict__ selfb, int N) {
    int idx = blockIdx.x * 256 + threadIdx.x;
    if (idx >= N * HID) return;
    int n = idx >> 5, c = idx & 31;
    const float* xrow = xin + (size_t)n * xstride;
    float s = 0.f;
#pragma unroll
    for (int i = 0; i < IN; i++) s = fmaf(xrow[i], loopw[i * HID + c], s);
    selfb[idx] = s + bias[c];
}

// one 32-lane half-wave per dst node; no atomics; coalesced 64B gathers
__global__ void agg_kernel(const int* __restrict__ row_start, const int* __restrict__ es,
                           const __half* __restrict__ xr, const float* __restrict__ selfb,
                           float* __restrict__ C, int col_off, int N) {
    int gid = blockIdx.x * blockDim.x + threadIdx.x;
    int d = gid >> 5;
    if (d >= N) return;
    int c = gid & 31;
    int beg = row_start[d], end = row_start[d + 1];
    float acc = 0.f;
    int i = beg;
    for (; i + 4 <= end; i += 4) {
        int p0 = es[i + 0], p1 = es[i + 1], p2 = es[i + 2], p3 = es[i + 3];
        float v0 = __half2float(xr[((size_t)(p0 >> 20) * N + (p0 & 0xFFFFF)) * HID + c]);
        float v1 = __half2float(xr[((size_t)(p1 >> 20) * N + (p1 & 0xFFFFF)) * HID + c]);
        float v2 = __half2float(xr[((size_t)(p2 >> 20) * N + (p2 & 0xFFFFF)) * HID + c]);
        float v3 = __half2float(xr[((size_t)(p3 >> 20) * N + (p3 & 0xFFFFF)) * HID + c]);
        acc += (v0 + v1) + (v2 + v3);
    }
    for (; i < end; i++) {
        int p = es[i];
        acc += __half2float(xr[((size_t)(p >> 20) * N + (p & 0xFFFFF)) * HID + c]);
    }
    float h = fast_tanh(acc + selfb[d * HID + c]);
    C[(size_t)d * 128 + col_off + c] = h;
}

// ---------------- final MLP ----------------

#define NG 16
__global__ void mlp_kernel(const float* __restrict__ C, const int* __restrict__ uid,
                           const int* __restrict__ vid, const float* __restrict__ w1,
                           const float* __restrict__ bl1, const float* __restrict__ w2,
                           const float* __restrict__ bl2, float* __restrict__ out, int G) {
    __shared__ float f[NG][256];
    __shared__ float red[NG][128];
    int g0 = blockIdx.x * NG;
    int t = threadIdx.x;
    for (int i = t; i < NG * 256; i += 128) {
        int g = i >> 8, k = i & 255;
        int gg = g0 + g;
        float v = 0.f;
        if (gg < G) {
            int node = (k < 128) ? uid[gg] : vid[gg];
            v = C[(size_t)node * 128 + (k & 127)];
        }
        f[g][k] = v;
    }
    __syncthreads();
    float acc[NG];
    float b1v = bl1[t];
#pragma unroll
    for (int g = 0; g < NG; g++) acc[g] = b1v;
    for (int k = 0; k < 256; k++) {
        float wv = w1[k * 128 + t];
#pragma unroll
        for (int g = 0; g < NG; g++) acc[g] = fmaf(f[g][k], wv, acc[g]);
    }
    float w2v = w2[t];
#pragma unroll
    for (int g = 0; g < NG; g++) red[g][t] = fmaxf(acc[g], 0.f) * w2v;
    __syncthreads();
    int g = t >> 3, part = t & 7;
    float s = 0.f;
#pragma unroll
    for (int i = 0; i < 16; i++) s += red[g][part * 16 + i];
    s += __shfl_down(s, 4, 8);
    s += __shfl_down(s, 2, 8);
    s += __shfl_down(s, 1, 8);
    if (part == 0 && g0 + g < G) out[g0 + g] = s + bl2[0];
}

extern "C" void kernel_launch(void* const* d_in, const int* in_sizes, int n_in,
                              void* d_out, int out_size, void* d_ws, size_t ws_size,
                              hipStream_t stream) {
    const float* x   = (const float*)d_in[0];
    const int* src   = (const int*)d_in[1];
    const int* dst   = (const int*)d_in[2];
    const int* etype = (const int*)d_in[3];
    const int* uid   = (const int*)d_in[4];
    const int* vid   = (const int*)d_in[5];
    int N = in_sizes[0] / 4;
    int E = in_sizes[1];
    int G = in_sizes[4];

    // workspace layout
    int* row_start = (int*)d_ws;                    // N+1
    int* cursor    = row_start + (N + 1);           // N+1 (doubles as deg before scan)
    int* bsum      = cursor + (N + 1);              // 512
    int* tmpex     = bsum + 512;                    // N
    int* es        = tmpex + N;                     // E
    __half* xr     = (__half*)(es + E);             // R*N*32 halves (32 MB)
    float* selfb   = (float*)(xr + (size_t)R * N * HID);  // N*32
    float* C       = selfb + (size_t)N * HID;       // N*128

    int nb = (N + 255) / 256;
    int eb = (E + 255) / 256;
    int nwb = (N * HID + 255) / 256;

    // ---- CSR build (once; reused by all 4 layers) ----
    zero_kernel<<<nb, 256, 0, stream>>>(cursor, N);
    hist_kernel<<<eb, 256, 0, stream>>>(dst, cursor, E);
    scan_partial<<<nb, 256, 0, stream>>>(cursor, tmpex, bsum, N);
    scan_bsum<<<1, 256, 0, stream>>>(bsum, nb);
    scan_add<<<nb, 256, 0, stream>>>(tmpex, bsum, row_start, cursor, N, E);
    scatter_kernel<<<eb, 256, 0, stream>>>(src, dst, etype, cursor, es, E);

    // ---- layers ----
    for (int l = 0; l < 4; l++) {
        const float* bases = (const float*)d_in[6 + l * 4];
        const float* comp  = (const float*)d_in[7 + l * 4];
        const float* loopw = (const float*)d_in[8 + l * 4];
        const float* bias  = (const float*)d_in[9 + l * 4];
        if (l == 0) {
            xr_kernel<4><<<dim3(nwb, R), 256, 0, stream>>>(x, 4, bases, comp, xr, N);
            selfb_kernel<4><<<nwb, 256, 0, stream>>>(x, 4, loopw, bias, selfb, N);
        } else {
            const float* cin = C + (l - 1) * HID;
            xr_kernel<32><<<dim3(nwb, R), 256, 0, stream>>>(cin, 128, bases, comp, xr, N);
            selfb_kernel<32><<<nwb, 256, 0, stream>>>(cin, 128, loopw, bias, selfb, N);
        }
        agg_kernel<<<nwb, 256, 0, stream>>>(row_start, es, xr, selfb, C, l * HID, N);
    }

    int gblocks = (G + NG - 1) / NG;
    mlp_kernel<<<gblocks, 128, 0, stream>>>(C, uid, vid,
                                            (const float*)d_in[22], (const float*)d_in[23],
                                            (const float*)d_in[24], (const float*)d_in[25],
                                            (float*)d_out, G);
}

// Round 3
// 1349.711 us; speedup vs baseline: 4.1034x; 1.1558x over previous
//
#include <hip/hip_runtime.h>
#include <hip/hip_fp16.h>

#define HID 32
#define R 5

__device__ __forceinline__ float fast_tanh(float x) {
    x = fminf(15.f, fmaxf(-15.f, x));
    float e = __expf(2.f * x);
    return (e - 1.f) / (e + 1.f);
}

// ---------------- CSR build (once per call; graph static across layers) ----------------

__global__ void zero_kernel(int* p, int n) {
    int i = blockIdx.x * blockDim.x + threadIdx.x;
    if (i < n) p[i] = 0;
}

__global__ void hist_kernel(const int* __restrict__ dst, int* __restrict__ deg, int E) {
    int e = blockIdx.x * blockDim.x + threadIdx.x;
    if (e < E) atomicAdd(&deg[dst[e]], 1);
}

__global__ void scan_partial(const int* __restrict__ deg, int* __restrict__ tmpex,
                             int* __restrict__ bsum, int n) {
    __shared__ int sh[256];
    int i = blockIdx.x * 256 + threadIdx.x;
    int v = (i < n) ? deg[i] : 0;
    sh[threadIdx.x] = v;
    __syncthreads();
    for (int off = 1; off < 256; off <<= 1) {
        int t = 0;
        if (threadIdx.x >= off) t = sh[threadIdx.x - off];
        __syncthreads();
        if (threadIdx.x >= off) sh[threadIdx.x] += t;
        __syncthreads();
    }
    if (i < n) tmpex[i] = sh[threadIdx.x] - v;
    if (threadIdx.x == 255) bsum[blockIdx.x] = sh[255];
}

__global__ void scan_bsum(int* bsum, int nb) {
    __shared__ int sh[256];
    __shared__ int carry_sh;
    if (threadIdx.x == 0) carry_sh = 0;
    __syncthreads();
    for (int base = 0; base < nb; base += 256) {
        int i = base + threadIdx.x;
        int v = (i < nb) ? bsum[i] : 0;
        sh[threadIdx.x] = v;
        __syncthreads();
        for (int off = 1; off < 256; off <<= 1) {
            int t = 0;
            if (threadIdx.x >= off) t = sh[threadIdx.x - off];
            __syncthreads();
            if (threadIdx.x >= off) sh[threadIdx.x] += t;
            __syncthreads();
        }
        int carry = carry_sh;
        if (i < nb) bsum[i] = sh[threadIdx.x] - v + carry;
        int tot = sh[255];
        __syncthreads();
        if (threadIdx.x == 0) carry_sh = carry + tot;
        __syncthreads();
    }
}

__global__ void scan_add(const int* __restrict__ tmpex, const int* __restrict__ bsum,
                         int* __restrict__ row_start, int* __restrict__ cursor, int n, int E) {
    int i = blockIdx.x * 256 + threadIdx.x;
    if (i < n) {
        int v = tmpex[i] + bsum[blockIdx.x];
        row_start[i] = v;
        cursor[i] = v;
    }
    if (i == 0) row_start[n] = E;
}

__global__ void scatter_kernel(const int* __restrict__ src, const int* __restrict__ dst,
                               const int* __restrict__ etype, int* __restrict__ cursor,
                               int* __restrict__ es, int E) {
    int e = blockIdx.x * blockDim.x + threadIdx.x;
    if (e >= E) return;
    int pos = atomicAdd(&cursor[dst[e]], 1);
    es[pos] = src[e] | (etype[e] << 20);
}

// ---------------- per-layer kernels ----------------

// Fused: xr[r][n][:] for all 5 relations + selfb, one read of the input row.
template<int IN>
__global__ void xrsb_kernel(const float* __restrict__ xin, int xstride,
                            const float* __restrict__ bases,  // [2, IN, 32]
                            const float* __restrict__ comp,   // [R, 2]
                            const float* __restrict__ loopw,  // [IN, 32]
                            const float* __restrict__ bias,   // [32]
                            __half* __restrict__ xr, float* __restrict__ selfb, int N) {
    int idx = blockIdx.x * 256 + threadIdx.x;
    if (idx >= N * HID) return;
    int n = idx >> 5, c = idx & 31;
    const float* xrow = xin + (size_t)n * xstride;
    float xv[IN];
#pragma unroll
    for (int i = 0; i < IN; i++) xv[i] = xrow[i];
    float s = bias[c];
#pragma unroll
    for (int i = 0; i < IN; i++) s = fmaf(xv[i], loopw[i * HID + c], s);
    selfb[idx] = s;
#pragma unroll
    for (int r = 0; r < R; r++) {
        float c0 = comp[r * 2 + 0], c1 = comp[r * 2 + 1];
        float acc = 0.f;
#pragma unroll
        for (int i = 0; i < IN; i++) {
            float w = fmaf(c0, bases[i * HID + c], c1 * bases[(IN + i) * HID + c]);
            acc = fmaf(xv[i], w, acc);
        }
        xr[((size_t)r * N + n) * HID + c] = __float2half(acc);
    }
}

// 16 lanes per dst row, half2 loads, 8 edges in flight per lane.
__global__ void agg_kernel(const int* __restrict__ row_start, const int* __restrict__ es,
                           const __half* __restrict__ xr, const float* __restrict__ selfb,
                           float* __restrict__ C, int col_off, int N) {
    int gid = blockIdx.x * blockDim.x + threadIdx.x;
    int d = gid >> 4;
    if (d >= N) return;
    int c2 = gid & 15;   // half2 index: channels 2*c2, 2*c2+1
    int beg = row_start[d], end = row_start[d + 1];
    float accx = 0.f, accy = 0.f;
    int i = beg;
    for (; i + 8 <= end; i += 8) {
        int p[8];
#pragma unroll
        for (int k = 0; k < 8; k++) p[k] = es[i + k];
        __half2 v[8];
#pragma unroll
        for (int k = 0; k < 8; k++) {
            size_t row = (size_t)(p[k] >> 20) * N + (p[k] & 0xFFFFF);
            v[k] = ((const __half2*)(xr + row * HID))[c2];
        }
#pragma unroll
        for (int k = 0; k < 8; k++) {
            float2 f = __half22float2(v[k]);
            accx += f.x;
            accy += f.y;
        }
    }
    for (; i < end; i++) {
        int p = es[i];
        size_t row = (size_t)(p >> 20) * N + (p & 0xFFFFF);
        float2 f = __half22float2(((const __half2*)(xr + row * HID))[c2]);
        accx += f.x;
        accy += f.y;
    }
    int c = c2 * 2;
    const float2 sb = *(const float2*)(selfb + (size_t)d * HID + c);
    float h0 = fast_tanh(accx + sb.x);
    float h1 = fast_tanh(accy + sb.y);
    *(float2*)(C + (size_t)d * 128 + col_off + c) = make_float2(h0, h1);
}

// ---------------- final MLP ----------------

#define NG 16
__global__ void mlp_kernel(const float* __restrict__ C, const int* __restrict__ uid,
                           const int* __restrict__ vid, const float* __restrict__ w1,
                           const float* __restrict__ bl1, const float* __restrict__ w2,
                           const float* __restrict__ bl2, float* __restrict__ out, int G) {
    __shared__ float f[NG][256];
    __shared__ float red[NG][128];
    int g0 = blockIdx.x * NG;
    int t = threadIdx.x;
    for (int i = t; i < NG * 256; i += 128) {
        int g = i >> 8, k = i & 255;
        int gg = g0 + g;
        float v = 0.f;
        if (gg < G) {
            int node = (k < 128) ? uid[gg] : vid[gg];
            v = C[(size_t)node * 128 + (k & 127)];
        }
        f[g][k] = v;
    }
    __syncthreads();
    float acc[NG];
    float b1v = bl1[t];
#pragma unroll
    for (int g = 0; g < NG; g++) acc[g] = b1v;
    for (int k = 0; k < 256; k++) {
        float wv = w1[k * 128 + t];
#pragma unroll
        for (int g = 0; g < NG; g++) acc[g] = fmaf(f[g][k], wv, acc[g]);
    }
    float w2v = w2[t];
#pragma unroll
    for (int g = 0; g < NG; g++) red[g][t] = fmaxf(acc[g], 0.f) * w2v;
    __syncthreads();
    int g = t >> 3, part = t & 7;
    float s = 0.f;
#pragma unroll
    for (int i = 0; i < 16; i++) s += red[g][part * 16 + i];
    s += __shfl_down(s, 4, 8);
    s += __shfl_down(s, 2, 8);
    s += __shfl_down(s, 1, 8);
    if (part == 0 && g0 + g < G) out[g0 + g] = s + bl2[0];
}

extern "C" void kernel_launch(void* const* d_in, const int* in_sizes, int n_in,
                              void* d_out, int out_size, void* d_ws, size_t ws_size,
                              hipStream_t stream) {
    const float* x   = (const float*)d_in[0];
    const int* src   = (const int*)d_in[1];
    const int* dst   = (const int*)d_in[2];
    const int* etype = (const int*)d_in[3];
    const int* uid   = (const int*)d_in[4];
    const int* vid   = (const int*)d_in[5];
    int N = in_sizes[0] / 4;
    int E = in_sizes[1];
    int G = in_sizes[4];

    // workspace layout
    int* row_start = (int*)d_ws;                    // N+1
    int* cursor    = row_start + (N + 1);           // N+1 (doubles as deg before scan)
    int* bsum      = cursor + (N + 1);              // 512
    int* tmpex     = bsum + 512;                    // N
    int* es        = tmpex + N;                     // E
    __half* xr     = (__half*)(es + E);             // R*N*32 halves (32 MB)
    float* selfb   = (float*)(xr + (size_t)R * N * HID);  // N*32
    float* C       = selfb + (size_t)N * HID;       // N*128

    int nb = (N + 255) / 256;
    int eb = (E + 255) / 256;
    int nwb = (N * HID + 255) / 256;
    int agg_blocks = (N * 16 + 255) / 256;

    // ---- CSR build (once; reused by all 4 layers) ----
    zero_kernel<<<nb, 256, 0, stream>>>(cursor, N);
    hist_kernel<<<eb, 256, 0, stream>>>(dst, cursor, E);
    scan_partial<<<nb, 256, 0, stream>>>(cursor, tmpex, bsum, N);
    scan_bsum<<<1, 256, 0, stream>>>(bsum, nb);
    scan_add<<<nb, 256, 0, stream>>>(tmpex, bsum, row_start, cursor, N, E);
    scatter_kernel<<<eb, 256, 0, stream>>>(src, dst, etype, cursor, es, E);

    // ---- layers ----
    for (int l = 0; l < 4; l++) {
        const float* bases = (const float*)d_in[6 + l * 4];
        const float* comp  = (const float*)d_in[7 + l * 4];
        const float* loopw = (const float*)d_in[8 + l * 4];
        const float* bias  = (const float*)d_in[9 + l * 4];
        if (l == 0)
            xrsb_kernel<4><<<nwb, 256, 0, stream>>>(x, 4, bases, comp, loopw, bias,
                                                    xr, selfb, N);
        else
            xrsb_kernel<32><<<nwb, 256, 0, stream>>>(C + (l - 1) * HID, 128, bases, comp,
                                                     loopw, bias, xr, selfb, N);
        agg_kernel<<<agg_blocks, 256, 0, stream>>>(row_start, es, xr, selfb, C, l * HID, N);
    }

    int gblocks = (G + NG - 1) / NG;
    mlp_kernel<<<gblocks, 128, 0, stream>>>(C, uid, vid,
                                            (const float*)d_in[22], (const float*)d_in[23],
                                            (const float*)d_in[24], (const float*)d_in[25],
                                            (float*)d_out, G);
}

// Round 4
// 972.035 us; speedup vs baseline: 5.6978x; 1.3885x over previous
//
#include <hip/hip_runtime.h>
#include <hip/hip_fp16.h>

#define HID 32
#define R 5
#define BSH 8            // bucket shift: 256 nodes per bucket
#define BCAP 12288       // LDS staging capacity in bucketC (48 KB)

__device__ __forceinline__ float fast_tanh(float x) {
    x = fminf(15.f, fmaxf(-15.f, x));
    float e = __expf(2.f * x);
    return (e - 1.f) / (e + 1.f);
}

// ---------------- CSR build: bucketed 2-level counting sort ----------------

__global__ void zero_kernel(int* p, int n) {
    int i = blockIdx.x * blockDim.x + threadIdx.x;
    if (i < n) p[i] = 0;
}

// Pass A: bucket histogram via LDS (4096 edges per block)
__global__ void bucketA(const int* __restrict__ dst, int* __restrict__ bucket_cnt,
                        int E, int K) {
    __shared__ int h[512];
    for (int i = threadIdx.x; i < K; i += 256) h[i] = 0;
    __syncthreads();
    int base = blockIdx.x * 4096;
#pragma unroll
    for (int k = 0; k < 16; k++) {
        int e = base + k * 256 + threadIdx.x;
        if (e < E) atomicAdd(&h[dst[e] >> BSH], 1);
    }
    __syncthreads();
    for (int i = threadIdx.x; i < K; i += 256)
        if (h[i]) atomicAdd(&bucket_cnt[i], h[i]);
}

// single block: exclusive scan of bucket counts -> bucket_base, cursor
__global__ void scan_buckets(const int* __restrict__ bucket_cnt, int* __restrict__ bucket_base,
                             int* __restrict__ cursor, int K, int E) {
    __shared__ int sh[512];
    int t = threadIdx.x;
    int v = (t < K) ? bucket_cnt[t] : 0;
    sh[t] = v;
    __syncthreads();
    for (int off = 1; off < 512; off <<= 1) {
        int tv = 0;
        if (t >= off) tv = sh[t - off];
        __syncthreads();
        if (t >= off) sh[t] += tv;
        __syncthreads();
    }
    if (t < K) {
        int b = sh[t] - v;
        bucket_base[t] = b;
        cursor[t] = b;
    }
    if (t == 511) bucket_base[K] = sh[511];   // == E
}

// Pass B: scatter edges into bucket-contiguous tmp, packed (ld<<20 | et<<17 | src)
__global__ void bucketB(const int* __restrict__ src, const int* __restrict__ dst,
                        const int* __restrict__ etype, int* __restrict__ cursor,
                        int* __restrict__ tmp, int E) {
    __shared__ int cnt[512];
    int tid = threadIdx.x;
    for (int i = tid; i < 512; i += 256) cnt[i] = 0;
    __syncthreads();
    int base = blockIdx.x * 4096;
    int lrank[16], pk[16], bk[16];
#pragma unroll
    for (int k = 0; k < 16; k++) {
        int e = base + k * 256 + tid;
        if (e < E) {
            int d = dst[e];
            int b = d >> BSH;
            bk[k] = b;
            pk[k] = src[e] | (etype[e] << 17) | ((d & 255) << 20);
            lrank[k] = atomicAdd(&cnt[b], 1);
        } else {
            bk[k] = -1;
        }
    }
    __syncthreads();
    for (int i = tid; i < 512; i += 256) {
        int c = cnt[i];
        if (c) cnt[i] = atomicAdd(&cursor[i], c);   // cnt now holds global base
    }
    __syncthreads();
#pragma unroll
    for (int k = 0; k < 16; k++) {
        if (bk[k] >= 0) tmp[cnt[bk[k]] + lrank[k]] = pk[k];
    }
}

// Pass C: per-bucket counting sort in LDS; emits es (src|et<<20) and row_start
__global__ void bucketC(const int* __restrict__ bucket_base, const int* __restrict__ tmp,
                        int* __restrict__ es, int* __restrict__ row_start,
                        int N, int E, int K) {
    __shared__ int stor[BCAP];
    __shared__ int hist[256];
    __shared__ int sc[256];
    __shared__ int cur[256];
    int b = blockIdx.x;
    int tid = threadIdx.x;
    int beg = bucket_base[b], end = bucket_base[b + 1];
    int cnt = end - beg;
    hist[tid] = 0;
    __syncthreads();
    for (int i = tid; i < cnt; i += 256) {
        int p = tmp[beg + i];
        if (i < BCAP) stor[i] = p;
        atomicAdd(&hist[p >> 20], 1);
    }
    __syncthreads();
    int v = hist[tid];
    sc[tid] = v;
    __syncthreads();
    for (int off = 1; off < 256; off <<= 1) {
        int tv = 0;
        if (tid >= off) tv = sc[tid - off];
        __syncthreads();
        if (tid >= off) sc[tid] += tv;
        __syncthreads();
    }
    int excl = sc[tid] - v;
    int d = (b << BSH) + tid;
    if (d < N) row_start[d] = beg + excl;
    if (b == K - 1 && tid == 0) row_start[N] = E;
    cur[tid] = beg + excl;
    __syncthreads();
    for (int i = tid; i < cnt; i += 256) {
        int p = (i < BCAP) ? stor[i] : tmp[beg + i];
        int ld = p >> 20;
        int pos = atomicAdd(&cur[ld], 1);
        es[pos] = (p & 0x1FFFF) | (((p >> 17) & 7) << 20);
    }
}

// ---------------- per-layer kernels ----------------

template<int IN>
__global__ void xrsb_kernel(const float* __restrict__ xin, int xstride,
                            const float* __restrict__ bases,  // [2, IN, 32]
                            const float* __restrict__ comp,   // [R, 2]
                            const float* __restrict__ loopw,  // [IN, 32]
                            const float* __restrict__ bias,   // [32]
                            __half* __restrict__ xr, float* __restrict__ selfb, int N) {
    int idx = blockIdx.x * 256 + threadIdx.x;
    if (idx >= N * HID) return;
    int n = idx >> 5, c = idx & 31;
    const float* xrow = xin + (size_t)n * xstride;
    float xv[IN];
#pragma unroll
    for (int i = 0; i < IN; i++) xv[i] = xrow[i];
    float s = bias[c];
#pragma unroll
    for (int i = 0; i < IN; i++) s = fmaf(xv[i], loopw[i * HID + c], s);
    selfb[idx] = s;
#pragma unroll
    for (int r = 0; r < R; r++) {
        float c0 = comp[r * 2 + 0], c1 = comp[r * 2 + 1];
        float acc = 0.f;
#pragma unroll
        for (int i = 0; i < IN; i++) {
            float w = fmaf(c0, bases[i * HID + c], c1 * bases[(IN + i) * HID + c]);
            acc = fmaf(xv[i], w, acc);
        }
        xr[((size_t)r * N + n) * HID + c] = __float2half(acc);
    }
}

// 8 lanes per dst row, uint2 (4-half) loads, 8 edges in flight -> 64 lines/wave
__global__ void agg_kernel(const int* __restrict__ row_start, const int* __restrict__ es,
                           const __half* __restrict__ xr, const float* __restrict__ selfb,
                           float* __restrict__ C, int col_off, int N) {
    int gid = blockIdx.x * blockDim.x + threadIdx.x;
    int d = gid >> 3;
    if (d >= N) return;
    int c4 = gid & 7;   // 4-channel group
    int beg = row_start[d], end = row_start[d + 1];
    float a0 = 0.f, a1 = 0.f, a2 = 0.f, a3 = 0.f;
    int i = beg;
    for (; i + 8 <= end; i += 8) {
        int p[8];
#pragma unroll
        for (int k = 0; k < 8; k++) p[k] = es[i + k];
        uint2 v[8];
#pragma unroll
        for (int k = 0; k < 8; k++) {
            size_t row = (size_t)(p[k] >> 20) * N + (p[k] & 0xFFFFF);
            v[k] = ((const uint2*)(xr + row * HID))[c4];
        }
#pragma unroll
        for (int k = 0; k < 8; k++) {
            float2 lo = __half22float2(*reinterpret_cast<__half2*>(&v[k].x));
            float2 hi = __half22float2(*reinterpret_cast<__half2*>(&v[k].y));
            a0 += lo.x; a1 += lo.y; a2 += hi.x; a3 += hi.y;
        }
    }
    for (; i < end; i++) {
        int p = es[i];
        size_t row = (size_t)(p >> 20) * N + (p & 0xFFFFF);
        uint2 vv = ((const uint2*)(xr + row * HID))[c4];
        float2 lo = __half22float2(*reinterpret_cast<__half2*>(&vv.x));
        float2 hi = __half22float2(*reinterpret_cast<__half2*>(&vv.y));
        a0 += lo.x; a1 += lo.y; a2 += hi.x; a3 += hi.y;
    }
    int c = c4 * 4;
    const float4 sb = *(const float4*)(selfb + (size_t)d * HID + c);
    float4 h;
    h.x = fast_tanh(a0 + sb.x);
    h.y = fast_tanh(a1 + sb.y);
    h.z = fast_tanh(a2 + sb.z);
    h.w = fast_tanh(a3 + sb.w);
    *(float4*)(C + (size_t)d * 128 + col_off + c) = h;
}

// ---------------- final MLP ----------------

#define NG 16
__global__ void mlp_kernel(const float* __restrict__ C, const int* __restrict__ uid,
                           const int* __restrict__ vid, const float* __restrict__ w1,
                           const float* __restrict__ bl1, const float* __restrict__ w2,
                           const float* __restrict__ bl2, float* __restrict__ out, int G) {
    __shared__ float f[NG][256];
    __shared__ float red[NG][128];
    int g0 = blockIdx.x * NG;
    int t = threadIdx.x;
    for (int i = t; i < NG * 256; i += 128) {
        int g = i >> 8, k = i & 255;
        int gg = g0 + g;
        float v = 0.f;
        if (gg < G) {
            int node = (k < 128) ? uid[gg] : vid[gg];
            v = C[(size_t)node * 128 + (k & 127)];
        }
        f[g][k] = v;
    }
    __syncthreads();
    float acc[NG];
    float b1v = bl1[t];
#pragma unroll
    for (int g = 0; g < NG; g++) acc[g] = b1v;
    for (int k = 0; k < 256; k++) {
        float wv = w1[k * 128 + t];
#pragma unroll
        for (int g = 0; g < NG; g++) acc[g] = fmaf(f[g][k], wv, acc[g]);
    }
    float w2v = w2[t];
#pragma unroll
    for (int g = 0; g < NG; g++) red[g][t] = fmaxf(acc[g], 0.f) * w2v;
    __syncthreads();
    int g = t >> 3, part = t & 7;
    float s = 0.f;
#pragma unroll
    for (int i = 0; i < 16; i++) s += red[g][part * 16 + i];
    s += __shfl_down(s, 4, 8);
    s += __shfl_down(s, 2, 8);
    s += __shfl_down(s, 1, 8);
    if (part == 0 && g0 + g < G) out[g0 + g] = s + bl2[0];
}

extern "C" void kernel_launch(void* const* d_in, const int* in_sizes, int n_in,
                              void* d_out, int out_size, void* d_ws, size_t ws_size,
                              hipStream_t stream) {
    const float* x   = (const float*)d_in[0];
    const int* src   = (const int*)d_in[1];
    const int* dst   = (const int*)d_in[2];
    const int* etype = (const int*)d_in[3];
    const int* uid   = (const int*)d_in[4];
    const int* vid   = (const int*)d_in[5];
    int N = in_sizes[0] / 4;
    int E = in_sizes[1];
    int G = in_sizes[4];
    int K = (N + 255) >> BSH;   // buckets

    // workspace layout (all offsets 256B-aligned)
    char* wp = (char*)d_ws;
    auto alloc = [&](size_t bytes) {
        char* p = wp;
        wp += (bytes + 255) & ~(size_t)255;
        return p;
    };
    int* row_start   = (int*)alloc((N + 1) * 4);
    int* bucket_cnt  = (int*)alloc(512 * 4);
    int* bucket_base = (int*)alloc(513 * 4);
    int* cursor      = (int*)alloc(512 * 4);
    int* es          = (int*)alloc((size_t)E * 4);
    __half* xr       = (__half*)alloc((size_t)R * N * HID * 2);
    int* tmp         = (int*)xr;   // tmp (E ints) aliases xr region (written before xr)
    float* selfb     = (float*)alloc((size_t)N * HID * 4);
    float* C         = (float*)alloc((size_t)N * 128 * 4);

    int nwb = (N * HID + 255) / 256;
    int ebb = (E + 4095) / 4096;
    int agg_blocks = (N * 8 + 255) / 256;

    // ---- CSR build ----
    zero_kernel<<<2, 256, 0, stream>>>(bucket_cnt, 512);
    bucketA<<<ebb, 256, 0, stream>>>(dst, bucket_cnt, E, K);
    scan_buckets<<<1, 512, 0, stream>>>(bucket_cnt, bucket_base, cursor, K, E);
    bucketB<<<ebb, 256, 0, stream>>>(src, dst, etype, cursor, tmp, E);
    bucketC<<<K, 256, 0, stream>>>(bucket_base, tmp, es, row_start, N, E, K);

    // ---- layers ----
    for (int l = 0; l < 4; l++) {
        const float* bases = (const float*)d_in[6 + l * 4];
        const float* comp  = (const float*)d_in[7 + l * 4];
        const float* loopw = (const float*)d_in[8 + l * 4];
        const float* bias  = (const float*)d_in[9 + l * 4];
        if (l == 0)
            xrsb_kernel<4><<<nwb, 256, 0, stream>>>(x, 4, bases, comp, loopw, bias,
                                                    xr, selfb, N);
        else
            xrsb_kernel<32><<<nwb, 256, 0, stream>>>(C + (l - 1) * HID, 128, bases, comp,
                                                     loopw, bias, xr, selfb, N);
        agg_kernel<<<agg_blocks, 256, 0, stream>>>(row_start, es, xr, selfb, C, l * HID, N);
    }

    int gblocks = (G + NG - 1) / NG;
    mlp_kernel<<<gblocks, 128, 0, stream>>>(C, uid, vid,
                                            (const float*)d_in[22], (const float*)d_in[23],
                                            (const float*)d_in[24], (const float*)d_in[25],
                                            (float*)d_out, G);
}